// Round 1
// baseline (1010.747 us; speedup 1.0000x reference)
//
#include <hip/hip_runtime.h>
#include <math.h>

// Problem constants (match setup_inputs): B=4, S=2048, H=16, D=64.
#define BB 4
#define SS 2048
#define HH 16
#define DD 64

#define TB 256      // threads per block = query rows per block
#define KT 64       // key tile staged in LDS
#define KC 16       // key chunk per online-softmax rescale
#define LDSPAD 68   // pad 64 -> 68 floats: keeps 16B alignment, breaks pow2 bank stride

__global__ __launch_bounds__(TB)
void varlen_attn_f32(const float* __restrict__ q,
                     const float* __restrict__ k,
                     const float* __restrict__ v,
                     const int* __restrict__ mask,   // [B,S], nonzero = valid key
                     float* __restrict__ out)
{
    // grid.x = B * H * (S/TB)
    const int nq  = SS / TB;                  // q-tiles per (b,h) = 8
    const int bid = blockIdx.x;
    const int qt  = bid % nq;
    const int h   = (bid / nq) % HH;
    const int b   = bid / (nq * HH);
    const int t   = threadIdx.x;
    const int s_q = qt * TB + t;              // this thread's query row

    __shared__ float ks[KT][LDSPAD];
    __shared__ float vs[KT][LDSPAD];
    __shared__ int   msk[KT];
    __shared__ int   anyvalid;

    const float scale = 0.125f;               // 1/sqrt(64)

    // ---- load q row into registers (pre-scaled) ----
    const float* qrow = q + (((size_t)b * SS + s_q) * HH + h) * DD;
    float qr[DD];
#pragma unroll
    for (int i = 0; i < DD / 4; ++i) {
        const float4 t4 = reinterpret_cast<const float4*>(qrow)[i];
        qr[4*i+0] = t4.x * scale;
        qr[4*i+1] = t4.y * scale;
        qr[4*i+2] = t4.z * scale;
        qr[4*i+3] = t4.w * scale;
    }

    float o[DD];
#pragma unroll
    for (int d = 0; d < DD; ++d) o[d] = 0.0f;
    float m = -1e30f;
    float l = 0.0f;

    const size_t kv_stride = (size_t)HH * DD;                    // 1024 floats
    const float* kbase = k + (size_t)b * SS * kv_stride + (size_t)h * DD;
    const float* vbase = v + (size_t)b * SS * kv_stride + (size_t)h * DD;
    const int*   mbase = mask + (size_t)b * SS;

    const int r0 = t >> 4;            // staging: row 0..15
    const int c4 = (t & 15) * 4;      // staging: col 0,4,...,60

    for (int kt0 = 0; kt0 < SS; kt0 += KT) {
        __syncthreads();   // previous tile fully consumed before overwrite

        if (t < KT) msk[t] = mbase[kt0 + t];

        // stage K and V tiles: 64 rows x 64 cols, float4 per thread x 4 rows
#pragma unroll
        for (int it = 0; it < 4; ++it) {
            const int r = r0 + it * 16;
            const float4 k4 = *reinterpret_cast<const float4*>(
                kbase + (size_t)(kt0 + r) * kv_stride + c4);
            const float4 v4 = *reinterpret_cast<const float4*>(
                vbase + (size_t)(kt0 + r) * kv_stride + c4);
            *reinterpret_cast<float4*>(&ks[r][c4]) = k4;
            *reinterpret_cast<float4*>(&vs[r][c4]) = v4;
        }

        if (t == 0) {
            int a = 0;
#pragma unroll
            for (int i = 0; i < KT; ++i) a |= msk[i];
            anyvalid = a;
        }
        __syncthreads();
        if (!anyvalid) continue;      // fully padded tile: no work

        for (int c0 = 0; c0 < KT; c0 += KC) {
            // ---- scores for KC keys ----
            float sc[KC];
#pragma unroll
            for (int j = 0; j < KC; ++j) {
                float acc = 0.0f;
#pragma unroll
                for (int d = 0; d < DD; d += 4) {
                    const float4 k4 = *reinterpret_cast<const float4*>(&ks[c0 + j][d]);
                    acc += qr[d+0] * k4.x;
                    acc += qr[d+1] * k4.y;
                    acc += qr[d+2] * k4.z;
                    acc += qr[d+3] * k4.w;
                }
                sc[j] = msk[c0 + j] ? acc : -1e30f;
            }

            // ---- online softmax update (one rescale per chunk) ----
            float cmax = sc[0];
#pragma unroll
            for (int j = 1; j < KC; ++j) cmax = fmaxf(cmax, sc[j]);
            const float mnew = fmaxf(m, cmax);
            const float corr = __expf(m - mnew);
            m = mnew;
            l *= corr;
#pragma unroll
            for (int d = 0; d < DD; ++d) o[d] *= corr;

#pragma unroll
            for (int j = 0; j < KC; ++j) {
                const float p = __expf(sc[j] - mnew);
                l += p;
#pragma unroll
                for (int d = 0; d < DD; d += 4) {
                    const float4 v4 = *reinterpret_cast<const float4*>(&vs[c0 + j][d]);
                    o[d+0] += p * v4.x;
                    o[d+1] += p * v4.y;
                    o[d+2] += p * v4.z;
                    o[d+3] += p * v4.w;
                }
            }
        }
    }

    // ---- epilogue ----
    const float inv = 1.0f / l;
    float* orow = out + (((size_t)b * SS + s_q) * HH + h) * DD;
#pragma unroll
    for (int i = 0; i < DD / 4; ++i) {
        float4 w;
        w.x = o[4*i+0] * inv;
        w.y = o[4*i+1] * inv;
        w.z = o[4*i+2] * inv;
        w.w = o[4*i+3] * inv;
        reinterpret_cast<float4*>(orow)[i] = w;
    }
}

extern "C" void kernel_launch(void* const* d_in, const int* in_sizes, int n_in,
                              void* d_out, int out_size, void* d_ws, size_t ws_size,
                              hipStream_t stream) {
    const float* q    = (const float*)d_in[0];
    const float* k    = (const float*)d_in[1];
    const float* v    = (const float*)d_in[2];
    const int*   mask = (const int*)d_in[3];
    float* out = (float*)d_out;

    dim3 grid(BB * HH * (SS / TB));
    dim3 block(TB);
    hipLaunchKernelGGL(varlen_attn_f32, grid, block, 0, stream, q, k, v, mask, out);
}

// Round 2
// 226.041 us; speedup vs baseline: 4.4715x; 4.4715x over previous
//
#include <hip/hip_runtime.h>

// B=4, S=2048, H=16, D=64 varlen (key-padding) attention, f32 in/out.
// bf16 MFMA flash attention, swapped-operand layout (S^T = K*Q^T, O^T = VT*P^T)
// so online-softmax state (m, l) is lane-local (q = lane&31).
#define BB 4
#define SS 2048
#define HH 16
#define DD 64

#define NQW 4            // waves per block
#define QW  32           // queries per wave (32x32 MFMA)
#define QB  (NQW*QW)     // 128 queries per block
#define KVB 32           // keys per tile

// LDS row strides (bytes)
#define KRS 144          // K tile: 64 bf16 = 128B + 16 pad (XOR-swizzled reads)
#define VRS 72           // V^T tile: 32 bf16 = 64B + 8 pad (72B => 16 distinct banks)
#define PRS 72           // P tile: 32 bf16 + 8 pad

typedef short bf16x8 __attribute__((ext_vector_type(8)));
typedef float f32x16 __attribute__((ext_vector_type(16)));

__device__ __forceinline__ unsigned short f2bf(float x){
    union { float f; unsigned int u; } v; v.f = x;
    unsigned int u = v.u + 0x7fffu + ((v.u >> 16) & 1u);   // RNE
    return (unsigned short)(u >> 16);
}
__device__ __forceinline__ float bf2f(unsigned short h){
    union { unsigned int u; float f; } v; v.u = ((unsigned int)h) << 16;
    return v.f;
}
__device__ __forceinline__ float exp2fast(float x){
    float r;
    asm("v_exp_f32 %0, %1\n\ts_nop 0" : "=v"(r) : "v"(x));  // s_nop: TRANS->VALU hazard
    return r;
}

union FragU { uint2 u2[2]; bf16x8 v; };

__global__ __launch_bounds__(256)
void attn_mfma(const float* __restrict__ qg, const float* __restrict__ kg,
               const float* __restrict__ vg, const int* __restrict__ maskg,
               float* __restrict__ outg)
{
    __shared__ __align__(16) unsigned char kl_raw[KVB*KRS];   // 4.5 KB
    __shared__ __align__(16) unsigned char vt_raw[DD*VRS];    // 4.5 KB (V transposed, key-pairs packed)
    __shared__ __align__(16) unsigned char p_raw[QB*PRS];     // 9 KB (per-wave P)
    __shared__ int lsum_s[NQW];

    // bijective XCD swizzle: each XCD gets a contiguous wg range -> same (b,h) K/V stays in its L2
    const int nwg = BB*HH*(SS/QB);          // 1024
    int wg = (int)blockIdx.x;
    wg = (wg & 7) * (nwg >> 3) + (wg >> 3);
    const int qt = wg & 15;                 // 16 q-tiles per (b,h)
    const int bh = wg >> 4;
    const int h  = bh & (HH-1);
    const int b  = bh >> 4;

    const int t    = (int)threadIdx.x;
    const int wid  = t >> 6;
    const int lane = t & 63;
    const int lq   = lane & 31;             // this lane's q column
    const int lh   = lane >> 5;

    // ---- valid length L (mask is a prefix: L = sum) ----
    const int* mrow = maskg + b*SS;
    int part = 0;
    #pragma unroll
    for (int i = 0; i < 8; ++i) part += mrow[t*8 + i];
    #pragma unroll
    for (int off = 1; off < 64; off <<= 1) part += __shfl_xor(part, off);
    if (lane == 0) lsum_s[wid] = part;
    __syncthreads();
    const int L = lsum_s[0] + lsum_s[1] + lsum_s[2] + lsum_s[3];

    // ---- Q fragments (B-operand of swapped QK^T), scale+log2e folded, hi/lo split ----
    const int q0 = qt*QB + wid*QW + lq;
    const float* qrow = qg + ((size_t)((size_t)b*SS + q0)*HH + h)*DD;
    const float QSC = 0.125f * 1.44269504088896340736f;   // 1/sqrt(64) * log2(e)
    bf16x8 Qh[4], Ql[4];
    #pragma unroll
    for (int kc = 0; kc < 4; ++kc) {
        const float* p = qrow + kc*16 + lh*8;
        float4 a = *(const float4*)p;
        float4 c = *(const float4*)(p + 4);
        float x[8] = {a.x,a.y,a.z,a.w,c.x,c.y,c.z,c.w};
        #pragma unroll
        for (int e = 0; e < 8; ++e) {
            float s = x[e] * QSC;
            unsigned short hb = f2bf(s);
            Qh[kc][e] = (short)hb;
            Ql[kc][e] = (short)f2bf(s - bf2f(hb));
        }
    }

    f32x16 O0, O1;                           // O^T frags: col = q (lane-local), rows = d
    #pragma unroll
    for (int i = 0; i < 16; ++i) { O0[i] = 0.f; O1[i] = 0.f; }
    float m = -1e30f, lp = 0.f;

    const size_t kvstride = (size_t)HH*DD;
    const float* kbase = kg + ((size_t)b*SS*HH + h)*(size_t)DD;
    const float* vbase = vg + ((size_t)b*SS*HH + h)*(size_t)DD;

    const int skr = t >> 3;                  // staging key row 0..31
    const int sc8 = (t & 7) * 8;             // staging d-col block
    const int spar = skr & 1;
    const int skp  = skr >> 1;               // key-pair index 0..15

    const int nt = (L + KVB - 1) / KVB;      // skip fully-masked tiles
    for (int it = 0; it < nt; ++it) {
        const int kt0 = it * KVB;
        __syncthreads();                     // previous tile fully consumed

        // ---- stage K tile: bf16 rows [32][KRS], XOR swizzle on 16B slots ----
        {
            const float* p = kbase + (size_t)(kt0 + skr)*kvstride + sc8;
            float4 a = *(const float4*)p;
            float4 c = *(const float4*)(p + 4);
            float x[8] = {a.x,a.y,a.z,a.w,c.x,c.y,c.z,c.w};
            bf16x8 kv;
            #pragma unroll
            for (int e = 0; e < 8; ++e) kv[e] = (short)f2bf(x[e]);
            unsigned off = (unsigned)skr*KRS + (unsigned)sc8*2u;
            off ^= ((unsigned)(skr>>3)&3u) << 4;
            *(bf16x8*)(kl_raw + off) = kv;
        }
        // ---- stage V^T tile: rows = d, key-pairs packed into dwords via shfl ----
        {
            const float* p = vbase + (size_t)(kt0 + skr)*kvstride + sc8;
            float4 a = *(const float4*)p;
            float4 c = *(const float4*)(p + 4);
            float x[8] = {a.x,a.y,a.z,a.w,c.x,c.y,c.z,c.w};
            unsigned mybits[8], rec[8];
            #pragma unroll
            for (int e = 0; e < 8; ++e) mybits[e] = f2bf(x[e]);
            #pragma unroll
            for (int e = 0; e < 8; ++e) rec[e] = (unsigned)__shfl_xor((int)mybits[e], 8);
            #pragma unroll
            for (int i2 = 0; i2 < 4; ++i2) {
                const int e2 = spar*4 + i2;          // even kr: d-cols 0..3, odd: 4..7
                unsigned lo = spar ? rec[e2] : mybits[e2];
                unsigned hi = spar ? mybits[e2] : rec[e2];
                unsigned dw = (lo & 0xffffu) | (hi << 16);
                *(unsigned*)(vt_raw + (unsigned)(sc8 + e2)*VRS + (unsigned)skp*4u) = dw;
            }
        }
        __syncthreads();

        // ---- QK^T swapped: S^T[key][q] = K * Q^T ; 2-term split (K*Qh + K*Ql) ----
        f32x16 S;
        #pragma unroll
        for (int i = 0; i < 16; ++i) S[i] = 0.f;
        #pragma unroll
        for (int kc = 0; kc < 4; ++kc) {
            unsigned off = (unsigned)lq*KRS + (unsigned)(kc*32 + lh*16);
            off ^= ((unsigned)(lq>>3)&3u) << 4;
            FragU kf;
            kf.v = *(const bf16x8*)(kl_raw + off);
            S = __builtin_amdgcn_mfma_f32_32x32x16_bf16(kf.v, Qh[kc], S, 0, 0, 0);
            S = __builtin_amdgcn_mfma_f32_32x32x16_bf16(kf.v, Ql[kc], S, 0, 0, 0);
        }

        // ---- varlen mask (boundary tile only; wave-uniform branch) ----
        if (kt0 + KVB > L) {
            #pragma unroll
            for (int r = 0; r < 16; ++r) {
                const int key = kt0 + (r&3) + 8*(r>>2) + 4*lh;
                if (key >= L) S[r] = -1e30f;
            }
        }

        // ---- online softmax, state lane-local (q = lq) ----
        float rmax = S[0];
        #pragma unroll
        for (int r = 1; r < 16; ++r) rmax = fmaxf(rmax, S[r]);
        rmax = fmaxf(rmax, __shfl_xor(rmax, 32));
        const float mnew = fmaxf(m, rmax);
        const float corr = exp2fast(m - mnew);
        m = mnew;
        float ps = 0.f;
        unsigned short pb[16];
        #pragma unroll
        for (int r = 0; r < 16; ++r) {
            float pv = exp2fast(S[r] - mnew);
            ps += pv;
            pb[r] = f2bf(pv);
        }
        lp = lp * corr + ps;
        #pragma unroll
        for (int i = 0; i < 16; ++i) { O0[i] *= corr; O1[i] *= corr; }

        // ---- P -> wave-private LDS row q=lq (4 runs of 4 consecutive keys) ----
        unsigned char* pw = p_raw + (unsigned)(wid*QW + lq)*PRS;
        #pragma unroll
        for (int run = 0; run < 4; ++run) {
            unsigned d0 = (unsigned)pb[4*run]   | ((unsigned)pb[4*run+1] << 16);
            unsigned d1 = (unsigned)pb[4*run+2] | ((unsigned)pb[4*run+3] << 16);
            *(uint2*)(pw + (unsigned)(8*run + 4*lh)*2u) = make_uint2(d0, d1);
        }

        // ---- PV swapped: O^T[d][q] += V^T * P ----
        const unsigned char* pr = p_raw + (unsigned)wid*QW*PRS + (unsigned)lq*PRS;
        #pragma unroll
        for (int kc = 0; kc < 2; ++kc) {
            const unsigned ko = (unsigned)(kc*32 + lh*16);
            FragU pf;
            pf.u2[0] = *(const uint2*)(pr + ko);
            pf.u2[1] = *(const uint2*)(pr + ko + 8);
            FragU v0, v1;
            v0.u2[0] = *(const uint2*)(vt_raw + (unsigned)lq*VRS + ko);
            v0.u2[1] = *(const uint2*)(vt_raw + (unsigned)lq*VRS + ko + 8);
            v1.u2[0] = *(const uint2*)(vt_raw + (unsigned)(lq+32)*VRS + ko);
            v1.u2[1] = *(const uint2*)(vt_raw + (unsigned)(lq+32)*VRS + ko + 8);
            O0 = __builtin_amdgcn_mfma_f32_32x32x16_bf16(v0.v, pf.v, O0, 0, 0, 0);
            O1 = __builtin_amdgcn_mfma_f32_32x32x16_bf16(v1.v, pf.v, O1, 0, 0, 0);
        }
    }

    // ---- epilogue: combine lane halves, normalize, store ----
    lp += __shfl_xor(lp, 32);
    const float inv = 1.0f / lp;
    float* orow = outg + ((size_t)((size_t)b*SS + q0)*HH + h)*DD;
    #pragma unroll
    for (int run = 0; run < 4; ++run) {
        float4 w0, w1;
        w0.x = O0[4*run+0]*inv; w0.y = O0[4*run+1]*inv;
        w0.z = O0[4*run+2]*inv; w0.w = O0[4*run+3]*inv;
        w1.x = O1[4*run+0]*inv; w1.y = O1[4*run+1]*inv;
        w1.z = O1[4*run+2]*inv; w1.w = O1[4*run+3]*inv;
        *(float4*)(orow + 8*run + 4*lh)      = w0;   // d = crow(4*run+i, lh)
        *(float4*)(orow + 32 + 8*run + 4*lh) = w1;
    }
}

extern "C" void kernel_launch(void* const* d_in, const int* in_sizes, int n_in,
                              void* d_out, int out_size, void* d_ws, size_t ws_size,
                              hipStream_t stream) {
    const float* q    = (const float*)d_in[0];
    const float* k    = (const float*)d_in[1];
    const float* v    = (const float*)d_in[2];
    const int*   mask = (const int*)d_in[3];
    float* out = (float*)d_out;

    dim3 grid(BB * HH * (SS / QB));   // 1024
    dim3 block(256);
    hipLaunchKernelGGL(attn_mfma, grid, block, 0, stream, q, k, v, mask, out);
}

// Round 3
// 115.315 us; speedup vs baseline: 8.7651x; 1.9602x over previous
//
#include <hip/hip_runtime.h>

// B=4, S=2048, H=16, D=64 varlen (key-padding) attention, f32 in/out.
// bf16 MFMA flash attention, swapped-operand layout (S^T = K*Q^T, O^T = V^T*P)
// R3: single-bf16 Q (4 QK MFMAs), double-buffered LDS with early global issue,
//     in-register P via cvt_pk_bf16 + permlane32_swap, defer-rescale, setprio.
#define BB 4
#define SS 2048
#define HH 16
#define DD 64

#define NQW 4            // waves per block
#define QW  32           // queries per wave
#define QB  (NQW*QW)     // 128 queries per block
#define KVB 32           // keys per tile

#define KRS 144          // K tile row stride (bytes): 128B data + 16 pad, XOR-swizzled
#define VRS 72           // V^T tile row stride (bytes): 64B data + 8 pad

typedef short bf16x8 __attribute__((ext_vector_type(8)));
typedef float f32x16 __attribute__((ext_vector_type(16)));

__device__ __forceinline__ unsigned cvtpk(float lo, float hi){
    unsigned r;
    asm("v_cvt_pk_bf16_f32 %0, %1, %2" : "=v"(r) : "v"(lo), "v"(hi));
    return r;
}

#if __has_builtin(__builtin_amdgcn_exp2f)
#define EXP2F(x) __builtin_amdgcn_exp2f(x)
#else
__device__ __forceinline__ float exp2_asm(float x){
    float r; asm("v_exp_f32 %0, %1\n\ts_nop 0" : "=v"(r) : "v"(x)); return r;
}
#define EXP2F(x) exp2_asm(x)
#endif

union FragU { unsigned u[4]; bf16x8 v; };

#if __has_builtin(__builtin_amdgcn_permlane32_swap)
__device__ __forceinline__ void plswap(unsigned &a, unsigned &b, int /*lh*/){
    auto r = __builtin_amdgcn_permlane32_swap(a, b, false, false);
    a = r[0]; b = r[1];
}
#else
__device__ __forceinline__ void plswap(unsigned &a, unsigned &b, int lh){
    unsigned sb = (unsigned)__shfl_xor((int)b, 32);
    unsigned sa = (unsigned)__shfl_xor((int)a, 32);
    unsigned na = lh ? sb : a;
    unsigned nb = lh ? b  : sa;
    a = na; b = nb;
}
#endif

__global__ __launch_bounds__(256)
void attn_mfma(const float* __restrict__ qg, const float* __restrict__ kg,
               const float* __restrict__ vg, const int* __restrict__ maskg,
               float* __restrict__ outg)
{
    __shared__ __align__(16) unsigned char kl_raw[2][KVB*KRS];   // 2 x 4.5 KB
    __shared__ __align__(16) unsigned char vt_raw[2][DD*VRS];    // 2 x 4.5 KB
    __shared__ int lsum_s[NQW];

    // bijective XCD swizzle (nwg = 1024, divisible by 8)
    const int nwg = BB*HH*(SS/QB);
    int wg = (int)blockIdx.x;
    wg = (wg & 7) * (nwg >> 3) + (wg >> 3);
    const int qt = wg & 15;
    const int bh = wg >> 4;
    const int h  = bh & (HH-1);
    const int b  = bh >> 4;

    const int t    = (int)threadIdx.x;
    const int wid  = t >> 6;
    const int lane = t & 63;
    const int lq   = lane & 31;
    const int lh   = lane >> 5;

    // ---- valid length L (prefix mask: L = sum) ----
    const int* mrow = maskg + b*SS;
    int part = 0;
    #pragma unroll
    for (int i = 0; i < 8; ++i) part += mrow[t*8 + i];
    #pragma unroll
    for (int off = 1; off < 64; off <<= 1) part += __shfl_xor(part, off);
    if (lane == 0) lsum_s[wid] = part;
    __syncthreads();
    const int L  = lsum_s[0] + lsum_s[1] + lsum_s[2] + lsum_s[3];
    const int nt = (L + KVB - 1) / KVB;

    // ---- Q fragment (B-operand of swapped QK^T), scale+log2e folded ----
    const int q0 = qt*QB + wid*QW + lq;
    const float* qrow = qg + ((size_t)((size_t)b*SS + q0)*HH + h)*DD;
    const float QSC = 0.125f * 1.44269504088896340736f;
    bf16x8 Qh[4];
    #pragma unroll
    for (int kc = 0; kc < 4; ++kc) {
        const float* p = qrow + kc*16 + lh*8;
        float4 a = *(const float4*)p;
        float4 c = *(const float4*)(p + 4);
        FragU f;
        f.u[0] = cvtpk(a.x*QSC, a.y*QSC);
        f.u[1] = cvtpk(a.z*QSC, a.w*QSC);
        f.u[2] = cvtpk(c.x*QSC, c.y*QSC);
        f.u[3] = cvtpk(c.z*QSC, c.w*QSC);
        Qh[kc] = f.v;
    }

    f32x16 O0, O1;
    #pragma unroll
    for (int i = 0; i < 16; ++i) { O0[i] = 0.f; O1[i] = 0.f; }
    float m = -1e30f, lp = 0.f;

    const size_t kvstride = (size_t)HH*DD;
    const float* kbase = kg + ((size_t)b*SS*HH + h)*(size_t)DD;
    const float* vbase = vg + ((size_t)b*SS*HH + h)*(size_t)DD;

    const int skr  = t >> 3;          // staging key row 0..31
    const int sc8  = (t & 7) * 8;     // staging d-col block
    const int spar = skr & 1;
    const int skp  = skr >> 1;

    float kx[8], vx[8];               // staging registers (f32)

    auto LOADT = [&](int kt0) {
        const float* kp = kbase + (size_t)(kt0 + skr)*kvstride + sc8;
        const float* vp = vbase + (size_t)(kt0 + skr)*kvstride + sc8;
        float4 a = *(const float4*)kp;  float4 c = *(const float4*)(kp + 4);
        kx[0]=a.x; kx[1]=a.y; kx[2]=a.z; kx[3]=a.w;
        kx[4]=c.x; kx[5]=c.y; kx[6]=c.z; kx[7]=c.w;
        float4 d = *(const float4*)vp;  float4 e = *(const float4*)(vp + 4);
        vx[0]=d.x; vx[1]=d.y; vx[2]=d.z; vx[3]=d.w;
        vx[4]=e.x; vx[5]=e.y; vx[6]=e.z; vx[7]=e.w;
    };

    auto CVTW = [&](int bsel) {
        // K tile: 4x cvt_pk -> one b128 write at XOR-swizzled slot
        FragU kf;
        #pragma unroll
        for (int j = 0; j < 4; ++j) kf.u[j] = cvtpk(kx[2*j], kx[2*j+1]);
        unsigned koff = (unsigned)skr*KRS + (unsigned)sc8*2u;
        koff ^= ((unsigned)(skr>>3)&3u) << 4;
        *(bf16x8*)(kl_raw[bsel] + koff) = kf.v;
        // V^T tile: exchange f32 with key-partner lane, pack key pairs via cvt_pk
        float rv[8];
        #pragma unroll
        for (int e = 0; e < 8; ++e) rv[e] = __shfl_xor(vx[e], 8);
        #pragma unroll
        for (int i2 = 0; i2 < 4; ++i2) {
            float lo = spar ? rv[4+i2] : vx[i2];     // even key -> low half
            float hi = spar ? vx[4+i2] : rv[i2];     // odd key  -> high half
            unsigned dw = cvtpk(lo, hi);
            unsigned row = (unsigned)(sc8 + (spar ? 4 : 0) + i2);
            *(unsigned*)(vt_raw[bsel] + row*VRS + (unsigned)skp*4u) = dw;
        }
    };

    // prologue: stage tile 0
    LOADT(0);
    CVTW(0);

    for (int it = 0; it < nt; ++it) {
        __syncthreads();                       // buf[cur] visible; buf[cur^1] free
        const int  cur  = it & 1;
        const bool more = (it + 1 < nt);
        if (more) LOADT((it + 1) * KVB);       // issue next tile's loads early

        // ---- QK^T swapped: S^T[key][q] = K * Q^T ----
        f32x16 S;
        #pragma unroll
        for (int i = 0; i < 16; ++i) S[i] = 0.f;
        __builtin_amdgcn_s_setprio(1);
        #pragma unroll
        for (int kc = 0; kc < 4; ++kc) {
            unsigned off = (unsigned)lq*KRS + (unsigned)(kc*32 + lh*16);
            off ^= ((unsigned)(lq>>3)&3u) << 4;
            FragU kf;
            kf.v = *(const bf16x8*)(kl_raw[cur] + off);
            S = __builtin_amdgcn_mfma_f32_32x32x16_bf16(kf.v, Qh[kc], S, 0, 0, 0);
        }
        __builtin_amdgcn_s_setprio(0);

        // ---- varlen boundary mask ----
        const int kt0 = it * KVB;
        if (kt0 + KVB > L) {
            #pragma unroll
            for (int r = 0; r < 16; ++r) {
                const int key = kt0 + (r&3) + 8*(r>>2) + 4*lh;
                if (key >= L) S[r] = -1e30f;
            }
        }

        // ---- online softmax (lane-local q), defer-rescale THR=8 ----
        float rmax = S[0];
        #pragma unroll
        for (int r = 1; r < 16; ++r) rmax = fmaxf(rmax, S[r]);
        rmax = fmaxf(rmax, __shfl_xor(rmax, 32));
        if (!__all(rmax <= m + 8.0f)) {
            const float mnew = fmaxf(m, rmax);
            const float corr = EXP2F(m - mnew);
            m = mnew;
            lp *= corr;
            #pragma unroll
            for (int i = 0; i < 16; ++i) { O0[i] *= corr; O1[i] *= corr; }
        }
        float p[16]; float ps = 0.f;
        #pragma unroll
        for (int r = 0; r < 16; ++r) { p[r] = EXP2F(S[r] - m); ps += p[r]; }
        lp += ps;

        // ---- P -> bf16 B-fragments fully in-register ----
        unsigned dw[8];
        #pragma unroll
        for (int j = 0; j < 8; ++j) dw[j] = cvtpk(p[2*j], p[2*j+1]);
        plswap(dw[0], dw[2], lh);  plswap(dw[1], dw[3], lh);
        plswap(dw[4], dw[6], lh);  plswap(dw[5], dw[7], lh);
        FragU B0, B1;
        B0.u[0]=dw[0]; B0.u[1]=dw[1]; B0.u[2]=dw[2]; B0.u[3]=dw[3];
        B1.u[0]=dw[4]; B1.u[1]=dw[5]; B1.u[2]=dw[6]; B1.u[3]=dw[7];

        // ---- PV swapped: O^T[d][q] += V^T * P ----
        const unsigned char* vtb = vt_raw[cur];
        __builtin_amdgcn_s_setprio(1);
        #pragma unroll
        for (int kc = 0; kc < 2; ++kc) {
            const unsigned ko = (unsigned)(kc*32 + lh*16);
            FragU va_, vb_;
            *(uint2*)&va_.u[0] = *(const uint2*)(vtb + (unsigned)lq*VRS + ko);
            *(uint2*)&va_.u[2] = *(const uint2*)(vtb + (unsigned)lq*VRS + ko + 8);
            *(uint2*)&vb_.u[0] = *(const uint2*)(vtb + (unsigned)(lq+32)*VRS + ko);
            *(uint2*)&vb_.u[2] = *(const uint2*)(vtb + (unsigned)(lq+32)*VRS + ko + 8);
            O0 = __builtin_amdgcn_mfma_f32_32x32x16_bf16(va_.v, kc ? B1.v : B0.v, O0, 0, 0, 0);
            O1 = __builtin_amdgcn_mfma_f32_32x32x16_bf16(vb_.v, kc ? B1.v : B0.v, O1, 0, 0, 0);
        }
        __builtin_amdgcn_s_setprio(0);

        // ---- convert + write next tile into the other buffer ----
        if (more) CVTW(cur ^ 1);
    }

    // ---- epilogue ----
    lp += __shfl_xor(lp, 32);
    const float inv = 1.0f / lp;
    float* orow = outg + ((size_t)((size_t)b*SS + q0)*HH + h)*DD;
    #pragma unroll
    for (int run = 0; run < 4; ++run) {
        float4 w0, w1;
        w0.x = O0[4*run+0]*inv; w0.y = O0[4*run+1]*inv;
        w0.z = O0[4*run+2]*inv; w0.w = O0[4*run+3]*inv;
        w1.x = O1[4*run+0]*inv; w1.y = O1[4*run+1]*inv;
        w1.z = O1[4*run+2]*inv; w1.w = O1[4*run+3]*inv;
        *(float4*)(orow + 8*run + 4*lh)      = w0;
        *(float4*)(orow + 32 + 8*run + 4*lh) = w1;
    }
}

extern "C" void kernel_launch(void* const* d_in, const int* in_sizes, int n_in,
                              void* d_out, int out_size, void* d_ws, size_t ws_size,
                              hipStream_t stream) {
    const float* q    = (const float*)d_in[0];
    const float* k    = (const float*)d_in[1];
    const float* v    = (const float*)d_in[2];
    const int*   mask = (const int*)d_in[3];
    float* out = (float*)d_out;

    dim3 grid(BB * HH * (SS / QB));   // 1024
    dim3 block(256);
    hipLaunchKernelGGL(attn_mfma, grid, block, 0, stream, q, k, v, mask, out);
}